// Round 1
// baseline (1713.899 us; speedup 1.0000x reference)
//
#include <hip/hip_runtime.h>
#include <stdint.h>

// SpikeAttention on MI355X (gfx950).
// xs/q/k/v are ms_act-quantized (multiples of 0.25 in [0,1]) -> EXACT in bf16.
// Weights split into hi+lo bf16 (residual ~2^-18) -> bf16 MFMA GEMMs at fp32-grade accuracy.
// kv = k^T v per head is exactly representable in fp32 (multiples of 1/16, <= 2^20) ->
// atomicAdd reduction is exact and deterministic.
// out = q @ U with U[h,d,j] = SCALE * sum_e kv[h,d,e]*Wp[j,h*64+e] (folds attn+proj into one GEMM).

typedef __attribute__((ext_vector_type(8))) __bf16 bf16x8;
typedef __attribute__((ext_vector_type(4))) float f32x4;

__device__ __forceinline__ float bf2f(unsigned short u) {
  return __builtin_bit_cast(float, (unsigned int)u << 16);
}
__device__ __forceinline__ unsigned short f2bf(float f) {
  unsigned int u = __builtin_bit_cast(unsigned int, f);
  u += 0x7FFFu + ((u >> 16) & 1u);
  return (unsigned short)(u >> 16);
}
__device__ __forceinline__ float ms_act(float x) {
  // floor(clamp(4x,0,4)+0.5)/4
  float t = fminf(fmaxf(4.0f * x, 0.0f), 4.0f);
  return floorf(t + 0.5f) * 0.25f;
}

#define GLD16(g, l)                                                                        \
  __builtin_amdgcn_global_load_lds((__attribute__((address_space(1))) void*)(const void*)(g), \
                                   (__attribute__((address_space(3))) void*)(l), 16, 0, 0)

// ---------------------------------------------------------------------------
// Prep: split Wq/Wk/Wv into hi/lo bf16, zero the kv accumulator.
// grid (1024, 3) x 256
__global__ __launch_bounds__(256) void split_w_kernel(
    const float* __restrict__ Wq, const float* __restrict__ Wk, const float* __restrict__ Wv,
    unsigned short* __restrict__ Whi, unsigned short* __restrict__ Wlo, float* __restrict__ kv) {
  const int tid = threadIdx.x;
  const int w = blockIdx.y;
  const float* W = (w == 0) ? Wq : (w == 1) ? Wk : Wv;
  const size_t base = (size_t)w * 1048576u;
  const size_t i = (size_t)(blockIdx.x * 256 + tid) * 4;
  float4 v = *(const float4*)&W[i];
  float vv[4] = {v.x, v.y, v.z, v.w};
  unsigned short h4[4], l4[4];
#pragma unroll
  for (int j = 0; j < 4; ++j) {
    unsigned short hi = f2bf(vv[j]);
    h4[j] = hi;
    l4[j] = f2bf(vv[j] - bf2f(hi));
  }
  *(uint2*)&Whi[base + i] = make_uint2((unsigned)h4[0] | ((unsigned)h4[1] << 16),
                                       (unsigned)h4[2] | ((unsigned)h4[3] << 16));
  *(uint2*)&Wlo[base + i] = make_uint2((unsigned)l4[0] | ((unsigned)l4[1] << 16),
                                       (unsigned)l4[2] | ((unsigned)l4[3] << 16));
  if (w == 0 && blockIdx.x < 64) {  // 16*64*64 floats = 65536
    ((float4*)kv)[blockIdx.x * 256 + tid] = make_float4(0.f, 0.f, 0.f, 0.f);
  }
}

// ---------------------------------------------------------------------------
// xs = ms_act(x), fp32 -> bf16 (exact). n4 = N*D/4 float4 chunks.
__global__ __launch_bounds__(256) void act_x_kernel(const float* __restrict__ x,
                                                    unsigned short* __restrict__ xs,
                                                    long long n4) {
  long long i = (long long)blockIdx.x * 256 + threadIdx.x;
  const long long stride = (long long)gridDim.x * 256;
  for (; i < n4; i += stride) {
    float4 v = ((const float4*)x)[i];
    unsigned int lo = (unsigned)f2bf(ms_act(v.x)) | ((unsigned)f2bf(ms_act(v.y)) << 16);
    unsigned int hi = (unsigned)f2bf(ms_act(v.z)) | ((unsigned)f2bf(ms_act(v.w)) << 16);
    ((uint2*)xs)[i] = make_uint2(lo, hi);
  }
}

// ---------------------------------------------------------------------------
// C = A @ (Bhi+Blo)^T, A:[65536,1024] bf16 (K-contig), B rows K-contig.
// 128x128 tile, BK=32, 4 waves (2x2), 16x16x32 bf16 MFMA, global_load_lds width 16.
// QUANT=1: C = ms_act(C) stored bf16.  QUANT=0: C stored fp32.
template <int QUANT>
__global__ __launch_bounds__(256, 2) void gemm_bt(const unsigned short* __restrict__ A,
                                                  const unsigned short* __restrict__ Bhi,
                                                  const unsigned short* __restrict__ Blo,
                                                  unsigned short* __restrict__ Cq,
                                                  float* __restrict__ Cf) {
  __shared__ unsigned short sA[128 * 32];
  __shared__ unsigned short sBh[128 * 32];
  __shared__ unsigned short sBl[128 * 32];

  const int tid = threadIdx.x;
  const int lane = tid & 63;
  const int wid = tid >> 6;
  const int wm = wid >> 1;
  const int wn = wid & 1;

  const size_t rowBase = (size_t)blockIdx.x * 128;
  const size_t colBase = (size_t)blockIdx.y * 128;

  f32x4 acc[4][4];
#pragma unroll
  for (int m = 0; m < 4; ++m)
#pragma unroll
    for (int n = 0; n < 4; ++n) acc[m][n] = (f32x4)(0.0f);

  const int r15 = lane & 15;
  const int ko = (lane >> 4) * 8;

  for (int ks = 0; ks < 32; ++ks) {
    const int k0 = ks * 32;
#pragma unroll
    for (int r = 0; r < 2; ++r) {
      const int e = r * 256 + tid;
      const int row = e >> 2;
      const int kc = (e & 3) * 8;
      GLD16(A + (rowBase + row) * 1024 + k0 + kc, sA + e * 8);
      GLD16(Bhi + (colBase + row) * 1024 + k0 + kc, sBh + e * 8);
      GLD16(Blo + (colBase + row) * 1024 + k0 + kc, sBl + e * 8);
    }
    __syncthreads();
    bf16x8 a[4], bh[4], bl[4];
#pragma unroll
    for (int m = 0; m < 4; ++m) a[m] = *(const bf16x8*)&sA[(wm * 64 + m * 16 + r15) * 32 + ko];
#pragma unroll
    for (int n = 0; n < 4; ++n) {
      bh[n] = *(const bf16x8*)&sBh[(wn * 64 + n * 16 + r15) * 32 + ko];
      bl[n] = *(const bf16x8*)&sBl[(wn * 64 + n * 16 + r15) * 32 + ko];
    }
#pragma unroll
    for (int m = 0; m < 4; ++m)
#pragma unroll
      for (int n = 0; n < 4; ++n) {
        acc[m][n] = __builtin_amdgcn_mfma_f32_16x16x32_bf16(a[m], bh[n], acc[m][n], 0, 0, 0);
        acc[m][n] = __builtin_amdgcn_mfma_f32_16x16x32_bf16(a[m], bl[n], acc[m][n], 0, 0, 0);
      }
    __syncthreads();
  }

  const int rq = (lane >> 4) * 4;
#pragma unroll
  for (int m = 0; m < 4; ++m)
#pragma unroll
    for (int n = 0; n < 4; ++n) {
      const size_t row0 = rowBase + wm * 64 + m * 16 + rq;
      const size_t col = colBase + wn * 64 + n * 16 + r15;
#pragma unroll
      for (int j = 0; j < 4; ++j) {
        const float v = acc[m][n][j];
        if (QUANT)
          Cq[(row0 + j) * 1024 + col] = f2bf(ms_act(v));
        else
          Cf[(row0 + j) * 1024 + col] = v;
      }
    }
}

// ---------------------------------------------------------------------------
// kv[h,d,e] += sum_n k[n,h,d]*v[n,h,e]; exact fp32, atomicAdd order-independent.
// grid (16 heads, 64 chunks of 1024 rows) x 256
__global__ __launch_bounds__(256) void kv_kernel(const unsigned short* __restrict__ K,
                                                 const unsigned short* __restrict__ V,
                                                 float* __restrict__ kv) {
  const int h = blockIdx.x;
  const long long n0 = (long long)blockIdx.y * 1024;
  const int tid = threadIdx.x;
  __shared__ unsigned short ks[16 * 64];
  __shared__ unsigned short vs[16 * 64];
  float acc[4][4] = {};
  const int db = (tid >> 4) * 4;
  const int eb = (tid & 15) * 4;
  const int idx = tid * 4;  // staging element index (nl = idx/64, c = idx%64)
  const int nl = idx >> 6, c = idx & 63;
  for (int s = 0; s < 64; ++s) {
    const long long nrow = n0 + s * 16 + nl;
    *(uint2*)&ks[idx] = *(const uint2*)&K[nrow * 1024 + h * 64 + c];
    *(uint2*)&vs[idx] = *(const uint2*)&V[nrow * 1024 + h * 64 + c];
    __syncthreads();
#pragma unroll
    for (int t = 0; t < 16; ++t) {
      float kd[4], ve[4];
#pragma unroll
      for (int i = 0; i < 4; ++i) kd[i] = bf2f(ks[t * 64 + db + i]);
#pragma unroll
      for (int j = 0; j < 4; ++j) ve[j] = bf2f(vs[t * 64 + eb + j]);
#pragma unroll
      for (int i = 0; i < 4; ++i)
#pragma unroll
        for (int j = 0; j < 4; ++j) acc[i][j] += kd[i] * ve[j];
    }
    __syncthreads();
  }
  float* base = kv + h * 4096;
#pragma unroll
  for (int i = 0; i < 4; ++i)
#pragma unroll
    for (int j = 0; j < 4; ++j) atomicAdd(&base[(db + i) * 64 + eb + j], acc[i][j]);
}

// ---------------------------------------------------------------------------
// Ut[j, h*64+d] = SCALE * sum_e kv[h,d,e] * Wp[j, h*64+e], split into hi/lo bf16.
// grid (16 heads, 16 j-blocks of 64) x 256
__global__ __launch_bounds__(256) void u_kernel(const float* __restrict__ kv,
                                                const float* __restrict__ Wp,
                                                unsigned short* __restrict__ Uhi,
                                                unsigned short* __restrict__ Ulo) {
  const int h = blockIdx.x;
  const int jb = blockIdx.y;
  const int tid = threadIdx.x;
  __shared__ float kvs[64 * 64];
  __shared__ float wps[64 * 64];
#pragma unroll
  for (int r = 0; r < 4; ++r) {
    const int f = tid + r * 256;  // float4 index, 1024 total
    ((float4*)kvs)[f] = ((const float4*)(kv + h * 4096))[f];
    ((float4*)wps)[f] = *(const float4*)&Wp[(size_t)(jb * 64 + (f >> 4)) * 1024 + h * 64 + (f & 15) * 4];
  }
  __syncthreads();
  const int db = (tid >> 4) * 4;
  const int jl = (tid & 15) * 4;
  float acc[4][4] = {};
  for (int e = 0; e < 64; ++e) {
    float kd[4], wj[4];
#pragma unroll
    for (int i = 0; i < 4; ++i) kd[i] = kvs[(db + i) * 64 + e];
#pragma unroll
    for (int j = 0; j < 4; ++j) wj[j] = wps[(jl + j) * 64 + e];
#pragma unroll
    for (int i = 0; i < 4; ++i)
#pragma unroll
      for (int j = 0; j < 4; ++j) acc[i][j] += kd[i] * wj[j];
  }
#pragma unroll
  for (int j = 0; j < 4; ++j)
#pragma unroll
    for (int i = 0; i < 4; ++i) {
      const float u = acc[i][j] * 0.25f;  // SCALE
      const unsigned short hi = f2bf(u);
      const unsigned short lo = f2bf(u - bf2f(hi));
      const size_t off = (size_t)(jb * 64 + jl + j) * 1024 + h * 64 + db + i;
      Uhi[off] = hi;
      Ulo[off] = lo;
    }
}

// ---------------------------------------------------------------------------
extern "C" void kernel_launch(void* const* d_in, const int* in_sizes, int n_in,
                              void* d_out, int out_size, void* d_ws, size_t ws_size,
                              hipStream_t stream) {
  const float* x = (const float*)d_in[0];
  const float* Wq = (const float*)d_in[1];
  const float* Wk = (const float*)d_in[2];
  const float* Wv = (const float*)d_in[3];
  const float* Wp = (const float*)d_in[4];
  float* out = (float*)d_out;

  char* ws = (char*)d_ws;
  const size_t NC2 = 134217728ull;  // 65536*1024 bf16
  unsigned short* xs = (unsigned short*)(ws);
  unsigned short* bufA = (unsigned short*)(ws + NC2);      // k, later reused for q
  unsigned short* bufB = (unsigned short*)(ws + 2 * NC2);  // v
  unsigned short* Whi = (unsigned short*)(ws + 3 * NC2);   // [3][1M] bf16
  unsigned short* Wlo = Whi + 3ull * 1048576;
  float* kvb = (float*)(ws + 3 * NC2 + 12582912ull);
  unsigned short* Uhi = (unsigned short*)(ws + 3 * NC2 + 12582912ull + 262144ull);
  unsigned short* Ulo = Uhi + 1048576;
  // total ws use: 419,692,544 bytes

  dim3 blk(256);
  split_w_kernel<<<dim3(1024, 3), blk, 0, stream>>>(Wq, Wk, Wv, Whi, Wlo, kvb);
  act_x_kernel<<<2048, blk, 0, stream>>>(x, xs, 16777216LL);
  // k = ms_act(xs @ Wk^T), v = ms_act(xs @ Wv^T)
  gemm_bt<1><<<dim3(512, 8), blk, 0, stream>>>(xs, Whi + 1048576, Wlo + 1048576, bufA, nullptr);
  gemm_bt<1><<<dim3(512, 8), blk, 0, stream>>>(xs, Whi + 2097152, Wlo + 2097152, bufB, nullptr);
  // kv = k^T v per head (exact)
  kv_kernel<<<dim3(16, 64), blk, 0, stream>>>(bufA, bufB, kvb);
  // q = ms_act(xs @ Wq^T) -> reuse bufA (k is dead)
  gemm_bt<1><<<dim3(512, 8), blk, 0, stream>>>(xs, Whi, Wlo, bufA, nullptr);
  // U = SCALE * kv @ Wp-slice, split hi/lo
  u_kernel<<<dim3(16, 16), blk, 0, stream>>>(kvb, Wp, Uhi, Ulo);
  // out = q @ U^T (fp32)
  gemm_bt<0><<<dim3(512, 8), blk, 0, stream>>>(bufA, Uhi, Ulo, nullptr, out);
}